// Round 4
// baseline (286.035 us; speedup 1.0000x reference)
//
#include <hip/hip_runtime.h>

typedef unsigned short u16;
typedef unsigned int u32;
typedef __attribute__((ext_vector_type(8))) __bf16 bf8v;   // MFMA A/B operand (8 bf16)
typedef __attribute__((ext_vector_type(8))) short s8v;     // same bits, for packing
typedef __attribute__((ext_vector_type(4))) float f4v;     // MFMA C/D (16x16)
typedef __attribute__((ext_vector_type(2))) __fp16 h2v;    // packed fp16 pair (cvt_pkrtz ret type)

#define DEV static __device__ __forceinline__

constexpr int NQ = 12544;   // B*H*W = 16*28*28
constexpr int MM = 8192;    // memory bank rows
constexpr int PP = 784;     // H*W
constexpr float EPSF = 1e-12f;
constexpr int D2S = 35;     // d2 scan stride: 35%32=3, gcd(3,32)=1 -> conflict-free reads

DEV u16 f2bf(float f) {  // RNE f32 -> bf16 (inputs are finite normals)
  u32 u = __float_as_uint(f);
  return (u16)((u + 0x7FFFu + ((u >> 16) & 1u)) >> 16);
}
DEV float bf2f(u16 h) { return __uint_as_float((u32)h << 16); }

// async 16B global -> LDS (lane-linear LDS dest, per-lane global src)
DEV void gl2lds16(const u16* g, u16* l) {
  __builtin_amdgcn_global_load_lds(
      (const __attribute__((address_space(1))) unsigned int*)(g),
      (__attribute__((address_space(3))) unsigned int*)(l), 16, 0, 0);
}

// branchless sorted insert: keep 5 smallest in a0<=..<=a4
DEV void ins5(float v, float& a0, float& a1, float& a2, float& a3, float& a4) {
  float hi;
  hi = fmaxf(v, a0); a0 = fminf(v, a0); v = hi;
  hi = fmaxf(v, a1); a1 = fminf(v, a1); v = hi;
  hi = fmaxf(v, a2); a2 = fminf(v, a2); v = hi;
  hi = fmaxf(v, a3); a3 = fminf(v, a3); v = hi;
  a4 = fminf(v, a4);
}

// ================= fused prep: all f32->bf16 packs =================
DEV void pack_bf16_dev(const float* __restrict__ x, u16* __restrict__ y, int bid, int tid) {
  int g = bid * 256 + tid;
  const float4* px = (const float4*)x + (size_t)g * 2;
  float4 a = px[0], b = px[1];
  s8v o;
  o[0] = (short)f2bf(a.x); o[1] = (short)f2bf(a.y); o[2] = (short)f2bf(a.z); o[3] = (short)f2bf(a.w);
  o[4] = (short)f2bf(b.x); o[5] = (short)f2bf(b.y); o[6] = (short)f2bf(b.z); o[7] = (short)f2bf(b.w);
  ((s8v*)y)[g] = o;
}

template<int C>
DEV void pack_mem_dev(const float* __restrict__ x, u16* __restrict__ y, float* __restrict__ nrm,
                      int bid, int tid) {
  int row = bid * 4 + (tid >> 6), lane = tid & 63;
  constexpr int E = C / 64;
  const float* src = x + (size_t)row * C + lane * E;
  float s = 0.f;
  if constexpr (E == 4) {
    float4 v = *(const float4*)src;
    s = v.x * v.x + v.y * v.y + v.z * v.z + v.w * v.w;
    u32 lo = (u32)f2bf(v.x) | ((u32)f2bf(v.y) << 16);
    u32 hi = (u32)f2bf(v.z) | ((u32)f2bf(v.w) << 16);
    ((uint2*)(y + (size_t)row * C))[lane] = make_uint2(lo, hi);
  } else {
    float2 v = *(const float2*)src;
    s = v.x * v.x + v.y * v.y;
    ((u32*)(y + (size_t)row * C))[lane] = (u32)f2bf(v.x) | ((u32)f2bf(v.y) << 16);
  }
#pragma unroll
  for (int m = 1; m < 64; m <<= 1) s += __shfl_xor(s, m);
  if (lane == 0) nrm[row] = s;
}

template<int C>
DEV void pack_q_dev(const float* __restrict__ q, u16* __restrict__ qfb, int bid, int tid) {
  int g = bid * 256 + tid;   // [0, NQ * C/8); NQ%256==0 so cc is block-uniform
  int n = g % NQ;
  int cc = g / NQ;
  int b = n / PP, p = n % PP;
  int c0 = cc * 8;
  const float* src = q + ((size_t)b * C + c0) * PP + p;   // lanes: consecutive p -> coalesced
  s8v o;
#pragma unroll
  for (int i = 0; i < 8; ++i) o[i] = (short)f2bf(src[(size_t)i * PP]);
  ((s8v*)qfb)[((size_t)n * C + c0) >> 3] = o;
}

__global__ __launch_bounds__(256) void k_prep(
    const float* __restrict__ q2, const float* __restrict__ q3,
    const float* __restrict__ mem2, const float* __restrict__ mem3,
    const float* __restrict__ icov2, const float* __restrict__ icov3,
    u16* __restrict__ qf2b, u16* __restrict__ qf3b,
    u16* __restrict__ m2b, u16* __restrict__ m3b,
    u16* __restrict__ ic2b, u16* __restrict__ ic3b,
    float* __restrict__ mn2, float* __restrict__ mn3) {
  int bid = blockIdx.x, tid = threadIdx.x;
  if (bid < 2048)       pack_mem_dev<128>(mem2, m2b, mn2, bid, tid);
  else if (bid < 4096)  pack_mem_dev<256>(mem3, m3b, mn3, bid - 2048, tid);
  else if (bid < 4104)  pack_bf16_dev(icov2, ic2b, bid - 4096, tid);
  else if (bid < 4136)  pack_bf16_dev(icov3, ic3b, bid - 4104, tid);
  else if (bid < 4920)  pack_q_dev<128>(q2, qf2b, bid - 4136, tid);
  else                  pack_q_dev<256>(q3, qf3b, bid - 4920, tid);
}

// ================= fused distances + per-row 5 smallest d2' =================
// Block: 128 query rows (4 waves x 32 rows), loops over MS = MM/NSPLIT bank rows in 64-col tiles.
// A (queries) in registers; B staged to LDS via global_load_lds (pre-swizzled source);
// d2' = mn - 2ab (NO qn -- row-constant, added in k_combine) packed fp16 in wave-private LDS.
template<int C, int NSPLIT, int WPEU>
__global__ __launch_bounds__(256, WPEU)
void k_score(const u16* __restrict__ qf, const u16* __restrict__ mem,
             const float* __restrict__ mn, float* __restrict__ kp) {
  constexpr int MT = 64, MS = MM / NSPLIT, NT = MS / MT;
  constexpr int CPR = C / 8;              // 16B chunks per bank row
  constexpr int SIT = (MT * CPR) / 256;   // global_load_lds iters per tile
  constexpr int RPI = 256 / CPR;          // rows staged per iter
  __shared__ alignas(16) u16 Bs[MT * C];
  __shared__ alignas(8) u32 d2w[4][32 * D2S];

  const int tid = threadIdx.x, wave = tid >> 6, lane = tid & 63;
  const int l15 = lane & 15, kb = lane >> 4, g4 = (lane >> 4) << 2;
  const int rt = blockIdx.x / NSPLIT, split = blockIdx.x % NSPLIT;
  const int row0 = rt * 128, mb0 = split * MS;

  // A fragments (loop-invariant) -> registers
  bf8v a[2][C / 32];
#pragma unroll
  for (int mb = 0; mb < 2; ++mb)
#pragma unroll
    for (int kk = 0; kk < C / 32; ++kk)
      a[mb][kk] = *(const bf8v*)(qf + (size_t)(row0 + wave * 32 + mb * 16 + l15) * C + ((kk * 4 + kb) << 3));

  // staging: LDS linear dest, source pre-swizzled so LDS[(r, cp)] holds global chunk cp^(r&7)
  const int srow = tid / CPR, scp = tid % CPR;
  const int sswz = (scp ^ (srow & 7)) << 3;
  u16* ldst = Bs + tid * 8;

  float s0 = 1e30f, s1 = 1e30f, s2 = 1e30f, s3 = 1e30f, s4 = 1e30f;
  float mnv[4];

  {  // prologue: stage tile 0 + its mn
    const u16* src = mem + (size_t)(mb0 + srow) * C + sswz;
#pragma unroll
    for (int it = 0; it < SIT; ++it) gl2lds16(src + (size_t)it * RPI * C, ldst + it * 2048);
#pragma unroll
    for (int cb = 0; cb < 4; ++cb) mnv[cb] = mn[mb0 + cb * 16 + l15];
  }
  __syncthreads();   // vmcnt drained -> Bs ready

  u32* myd2 = &d2w[wave][0];
  for (int mt = 0; mt < NT; ++mt) {
    // MFMA phase: acc[mb][cb] over K=C
    f4v acc[2][4];
#pragma unroll
    for (int mb = 0; mb < 2; ++mb)
#pragma unroll
      for (int cb = 0; cb < 4; ++cb) acc[mb][cb] = (f4v){0.f, 0.f, 0.f, 0.f};
#pragma unroll
    for (int kk = 0; kk < C / 32; ++kk) {
      bf8v b[4];
#pragma unroll
      for (int cb = 0; cb < 4; ++cb) {
        int brow = cb * 16 + l15;
        b[cb] = *(const bf8v*)(Bs + brow * C + (((kk * 4 + kb) ^ (brow & 7)) << 3));
      }
#pragma unroll
      for (int mb = 0; mb < 2; ++mb)
#pragma unroll
        for (int cb = 0; cb < 4; ++cb)
          acc[mb][cb] = __builtin_amdgcn_mfma_f32_16x16x32_bf16(a[mb][kk], b[cb], acc[mb][cb], 0, 0, 0);
    }
    // pack d2' = mn - 2*acc to fp16 pairs in wave-private LDS
#pragma unroll
    for (int mb = 0; mb < 2; ++mb)
#pragma unroll
      for (int p = 0; p < 2; ++p)
#pragma unroll
        for (int r = 0; r < 4; ++r) {
          float x0 = fmaf(-2.f, acc[mb][2 * p][r], mnv[2 * p]);
          float x1 = fmaf(-2.f, acc[mb][2 * p + 1][r], mnv[2 * p + 1]);
          h2v h = __builtin_amdgcn_cvt_pkrtz(x0, x1);
          myd2[(mb * 16 + g4 + r) * D2S + p * 16 + l15] = *(u32*)&h;
        }
    __syncthreads();   // all Bs reads done -> safe to restage
    if (mt + 1 < NT) {
      const u16* src = mem + (size_t)(mb0 + (mt + 1) * MT + srow) * C + sswz;
#pragma unroll
      for (int it = 0; it < SIT; ++it) gl2lds16(src + (size_t)it * RPI * C, ldst + it * 2048);
#pragma unroll
      for (int cb = 0; cb < 4; ++cb) mnv[cb] = mn[mb0 + (mt + 1) * MT + cb * 16 + l15];
    }
    // scan own wave's d2' (overlaps staging latency); 2 lanes per row, 32 candidates each
    {
      const u32* dw = myd2 + (lane >> 1) * D2S + (lane & 1) * 16;
#pragma unroll
      for (int j = 0; j < 16; j += 2) {
        uint2 ww = *(const uint2*)(dw + j);
        h2v h0 = *(h2v*)&ww.x, h1 = *(h2v*)&ww.y;
        float v0 = (float)h0[0], v1 = (float)h0[1];
        float v2 = (float)h1[0], v3 = (float)h1[1];
        float m01 = fminf(fminf(v0, v1), fminf(v2, v3));
        if (m01 < s4) {
          ins5(v0, s0, s1, s2, s3, s4);
          ins5(v1, s0, s1, s2, s3, s4);
          ins5(v2, s0, s1, s2, s3, s4);
          ins5(v3, s0, s1, s2, s3, s4);
        }
      }
    }
    __syncthreads();   // staging complete before next MFMA
  }

  // merge lane pairs (each row scanned by lanes 2k, 2k+1), write (qn added in combine)
  float r0 = __shfl_xor(s0, 1), r1 = __shfl_xor(s1, 1), r2 = __shfl_xor(s2, 1),
        r3 = __shfl_xor(s3, 1), r4 = __shfl_xor(s4, 1);
  ins5(r0, s0, s1, s2, s3, s4);
  ins5(r1, s0, s1, s2, s3, s4);
  ins5(r2, s0, s1, s2, s3, s4);
  ins5(r3, s0, s1, s2, s3, s4);
  ins5(r4, s0, s1, s2, s3, s4);
  if ((lane & 1) == 0) {
    int grow = row0 + wave * 32 + (lane >> 1);
    float* o = kp + ((size_t)split * NQ + grow) * 5;
    o[0] = s0; o[1] = s1; o[2] = s2; o[3] = s3; o[4] = s4;
  }
}

// ================= fused mid: q row-norms + Mahalanobis =================
template<int C>
DEV void rownorm_dev(const u16* __restrict__ x, float* __restrict__ out, int bid, int tid) {
  int row = bid * 4 + (tid >> 6);
  int lane = tid & 63;
  constexpr int E = C / 64;
  const u16* p = x + (size_t)row * C + lane * E;
  float s = 0.f;
#pragma unroll
  for (int i = 0; i < E; ++i) { float v = bf2f(p[i]); s += v * v; }
#pragma unroll
  for (int m = 1; m < 64; m <<= 1) s += __shfl_xor(s, m);
  if (lane == 0) out[row] = s;
}

template<int C>
DEV void maha_dev(const u16* __restrict__ qfb, const float* __restrict__ mu,
                  const u16* __restrict__ icovb, float* __restrict__ mh,
                  u16* As, float* muS, int bid, int tid) {
  constexpr int QT = 64, KCH = C / 8;
  int wave = tid >> 6, lane = tid & 63;
  int row0 = bid * QT;

  for (int i = tid; i < C; i += 256) muS[i] = mu[i];
  __syncthreads();
  for (int u = tid; u < QT * KCH; u += 256) {
    int r = u / KCH, cc = u % KCH;
    bf8v v = *(const bf8v*)(qfb + (size_t)(row0 + r) * C + cc * 8);
    s8v d;
#pragma unroll
    for (int i = 0; i < 8; ++i) d[i] = (short)f2bf((float)v[i] - muS[cc * 8 + i]);
    *(s8v*)(As + r * C + ((cc ^ (r & 7)) << 3)) = d;
  }
  __syncthreads();

  int arow = wave * 16 + (lane & 15);
  int kb = lane >> 4;
  float mm[4] = {0.f, 0.f, 0.f, 0.f};
#pragma unroll
  for (int cb = 0; cb < C / 16; ++cb) {
    f4v acc = (f4v){0.f, 0.f, 0.f, 0.f};
    int bcol = cb * 16 + (lane & 15);
#pragma unroll
    for (int kk = 0; kk < C / 32; ++kk) {
      int kc = kk * 4 + kb;
      bf8v a = *(const bf8v*)(As + arow * C + ((kc ^ (arow & 7)) << 3));
      bf8v b = *(const bf8v*)(icovb + (size_t)bcol * C + kc * 8);  // global, L2-hot
      acc = __builtin_amdgcn_mfma_f32_16x16x32_bf16(a, b, acc, 0, 0, 0);
    }
#pragma unroll
    for (int r = 0; r < 4; ++r) {
      int row = wave * 16 + (lane >> 4) * 4 + r;
      int col = cb * 16 + (lane & 15);
      float dv = bf2f(As[row * C + (((col >> 3) ^ (row & 7)) << 3) + (col & 7)]);
      mm[r] += acc[r] * dv;
    }
  }
#pragma unroll
  for (int r = 0; r < 4; ++r) {
    float v = mm[r];
    v += __shfl_xor(v, 1); v += __shfl_xor(v, 2);
    v += __shfl_xor(v, 4); v += __shfl_xor(v, 8);
    if ((lane & 15) == 0)
      mh[row0 + wave * 16 + (lane >> 4) * 4 + r] = sqrtf(fmaxf(v, EPSF));
  }
}

__global__ __launch_bounds__(256) void k_mid(
    const u16* __restrict__ qf2b, const u16* __restrict__ qf3b,
    const float* __restrict__ mean2, const float* __restrict__ mean3,
    const u16* __restrict__ ic2b, const u16* __restrict__ ic3b,
    float* __restrict__ qn2, float* __restrict__ qn3,
    float* __restrict__ mh2, float* __restrict__ mh3) {
  __shared__ alignas(16) u16 As[64 * 256];
  __shared__ float muS[256];
  int bid = blockIdx.x, tid = threadIdx.x;
  if (bid < 3136)       rownorm_dev<128>(qf2b, qn2, bid, tid);
  else if (bid < 6272)  rownorm_dev<256>(qf3b, qn3, bid - 3136, tid);
  else if (bid < 6468)  maha_dev<128>(qf2b, mean2, ic2b, mh2, As, muS, bid - 6272, tid);
  else                  maha_dev<256>(qf3b, mean3, ic3b, mh3, As, muS, bid - 6468, tid);
}

// ================= combine: merge knn splits (+qn), build maps =================
template<int S>
DEV float knn_merge(const float* kp, int n, float qv) {
  float t0 = 1e30f, t1 = 1e30f, t2 = 1e30f, t3 = 1e30f, t4 = 1e30f;
#pragma unroll
  for (int s = 0; s < S; ++s) {
    const float* p = kp + ((size_t)s * NQ + n) * 5;
#pragma unroll
    for (int i = 0; i < 5; ++i) ins5(p[i], t0, t1, t2, t3, t4);
  }
  return 0.2f * (sqrtf(fmaxf(t0 + qv, EPSF)) + sqrtf(fmaxf(t1 + qv, EPSF)) +
                 sqrtf(fmaxf(t2 + qv, EPSF)) + sqrtf(fmaxf(t3 + qv, EPSF)) +
                 sqrtf(fmaxf(t4 + qv, EPSF)));
}

__global__ __launch_bounds__(256) void k_combine(
    const float* __restrict__ kp2, const float* __restrict__ kp3,
    const float* __restrict__ qn2, const float* __restrict__ qn3,
    const float* __restrict__ mh2, const float* __restrict__ mh3,
    float* __restrict__ out) {
  int n = blockIdx.x * 256 + threadIdx.x;   // exact: 49*256 == NQ
  float m2v = 0.5f * (knn_merge<8>(kp2, n, qn2[n]) + mh2[n]);
  float m3v = 0.5f * (knn_merge<8>(kp3, n, qn3[n]) + mh3[n]);
  out[16 + n] = 0.5f * (m2v + m3v);
  out[16 + NQ + n] = m2v;
  out[16 + 2 * NQ + n] = m3v;
}

// ================= per-image top-10 mean over 784-pixel map =================
__global__ __launch_bounds__(256) void k_top10(const float* __restrict__ comb, float* __restrict__ pred) {
  __shared__ float vals[1024];
  __shared__ float rv[256];
  __shared__ int ri[256];
  __shared__ float ssum;
  int b = blockIdx.x, tid = threadIdx.x;
  for (int i = tid; i < 1024; i += 256) vals[i] = (i < PP) ? comb[b * PP + i] : -1e30f;
  if (tid == 0) ssum = 0.f;
  __syncthreads();
  for (int it = 0; it < 10; ++it) {
    float bv = -1e30f; int bi = 0;
    for (int i = tid; i < 1024; i += 256) { float v = vals[i]; if (v > bv) { bv = v; bi = i; } }
    rv[tid] = bv; ri[tid] = bi;
    __syncthreads();
    for (int s = 128; s; s >>= 1) {
      if (tid < s && rv[tid + s] > rv[tid]) { rv[tid] = rv[tid + s]; ri[tid] = ri[tid + s]; }
      __syncthreads();
    }
    if (tid == 0) { ssum += rv[0]; vals[ri[0]] = -1e30f; }
    __syncthreads();
  }
  if (tid == 0) pred[b] = ssum * 0.1f;
}

extern "C" void kernel_launch(void* const* d_in, const int* in_sizes, int n_in,
                              void* d_out, int out_size, void* d_ws, size_t ws_size,
                              hipStream_t stream) {
  const float* q2    = (const float*)d_in[0];
  const float* q3    = (const float*)d_in[1];
  const float* mem2  = (const float*)d_in[2];
  const float* mem3  = (const float*)d_in[3];
  const float* mean2 = (const float*)d_in[4];
  const float* mean3 = (const float*)d_in[5];
  const float* icov2 = (const float*)d_in[6];
  const float* icov3 = (const float*)d_in[7];
  float* out = (float*)d_out;

  char* w = (char*)d_ws;
  auto alloc = [&](size_t bytes) { void* p = (void*)w; w += (bytes + 255) & ~(size_t)255; return p; };
  u16* qf2b = (u16*)alloc((size_t)NQ * 128 * 2);
  u16* qf3b = (u16*)alloc((size_t)NQ * 256 * 2);
  u16* m2b  = (u16*)alloc((size_t)MM * 128 * 2);
  u16* m3b  = (u16*)alloc((size_t)MM * 256 * 2);
  u16* ic2b = (u16*)alloc((size_t)128 * 128 * 2);
  u16* ic3b = (u16*)alloc((size_t)256 * 256 * 2);
  float* qn2 = (float*)alloc((size_t)NQ * 4);
  float* qn3 = (float*)alloc((size_t)NQ * 4);
  float* mn2 = (float*)alloc((size_t)MM * 4);
  float* mn3 = (float*)alloc((size_t)MM * 4);
  float* kp2 = (float*)alloc((size_t)8 * NQ * 5 * 4);
  float* kp3 = (float*)alloc((size_t)8 * NQ * 5 * 4);
  float* mh2 = (float*)alloc((size_t)NQ * 4);
  float* mh3 = (float*)alloc((size_t)NQ * 4);

  // fused prep: pack_mem2(2048) | pack_mem3(2048) | icov2(8) | icov3(32) | pack_q2(784) | pack_q3(1568)
  k_prep<<<6488, 256, 0, stream>>>(q2, q3, mem2, mem3, icov2, icov3,
                                   qf2b, qf3b, m2b, m3b, ic2b, ic3b, mn2, mn3);

  // 784 blocks each ~= 3.06 blocks/CU (matches LDS capacity of 3-4 blocks/CU)
  k_score<256, 8, 3><<<(NQ / 128) * 8, 256, 0, stream>>>(qf3b, m3b, mn3, kp3);
  k_score<128, 8, 4><<<(NQ / 128) * 8, 256, 0, stream>>>(qf2b, m2b, mn2, kp2);

  // fused mid: rownorm_q2(3136) | rownorm_q3(3136) | maha128(196) | maha256(196)
  k_mid<<<6664, 256, 0, stream>>>(qf2b, qf3b, mean2, mean3, ic2b, ic3b, qn2, qn3, mh2, mh3);

  k_combine<<<NQ / 256, 256, 0, stream>>>(kp2, kp3, qn2, qn3, mh2, mh3, out);
  k_top10<<<16, 256, 0, stream>>>(out + 16, out);

  (void)in_sizes; (void)n_in; (void)out_size; (void)ws_size;
}

// Round 5
// 240.880 us; speedup vs baseline: 1.1875x; 1.1875x over previous
//
#include <hip/hip_runtime.h>

typedef unsigned short u16;
typedef unsigned int u32;
typedef __attribute__((ext_vector_type(8))) __bf16 bf8v;   // MFMA A/B operand (8 bf16)
typedef __attribute__((ext_vector_type(8))) short s8v;     // same bits, for packing
typedef __attribute__((ext_vector_type(4))) float f4v;     // MFMA C/D (16x16)

#define DEV static __device__ __forceinline__

constexpr int NQ = 12544;   // B*H*W = 16*28*28
constexpr int MM = 8192;    // memory bank rows
constexpr int PP = 784;     // H*W
constexpr float EPSF = 1e-12f;

DEV u16 f2bf(float f) {  // RNE f32 -> bf16 (inputs are finite normals)
  u32 u = __float_as_uint(f);
  return (u16)((u + 0x7FFFu + ((u >> 16) & 1u)) >> 16);
}
DEV float bf2f(u16 h) { return __uint_as_float((u32)h << 16); }

// async 16B global -> LDS (lane-linear LDS dest, per-lane global src)
DEV void gl2lds16(const u16* g, u16* l) {
  __builtin_amdgcn_global_load_lds(
      (const __attribute__((address_space(1))) unsigned int*)(g),
      (__attribute__((address_space(3))) unsigned int*)(l), 16, 0, 0);
}

// branchless sorted insert: keep 5 smallest in a0<=..<=a4
DEV void ins5(float v, float& a0, float& a1, float& a2, float& a3, float& a4) {
  float hi;
  hi = fmaxf(v, a0); a0 = fminf(v, a0); v = hi;
  hi = fmaxf(v, a1); a1 = fminf(v, a1); v = hi;
  hi = fmaxf(v, a2); a2 = fminf(v, a2); v = hi;
  hi = fmaxf(v, a3); a3 = fminf(v, a3); v = hi;
  a4 = fminf(v, a4);
}

// ================= fused prep: all f32->bf16 packs =================
DEV void pack_bf16_dev(const float* __restrict__ x, u16* __restrict__ y, int bid, int tid) {
  int g = bid * 256 + tid;
  const float4* px = (const float4*)x + (size_t)g * 2;
  float4 a = px[0], b = px[1];
  s8v o;
  o[0] = (short)f2bf(a.x); o[1] = (short)f2bf(a.y); o[2] = (short)f2bf(a.z); o[3] = (short)f2bf(a.w);
  o[4] = (short)f2bf(b.x); o[5] = (short)f2bf(b.y); o[6] = (short)f2bf(b.z); o[7] = (short)f2bf(b.w);
  ((s8v*)y)[g] = o;
}

template<int C>
DEV void pack_mem_dev(const float* __restrict__ x, u16* __restrict__ y, float* __restrict__ nrm,
                      int bid, int tid) {
  int row = bid * 4 + (tid >> 6), lane = tid & 63;
  constexpr int E = C / 64;
  const float* src = x + (size_t)row * C + lane * E;
  float s = 0.f;
  if constexpr (E == 4) {
    float4 v = *(const float4*)src;
    s = v.x * v.x + v.y * v.y + v.z * v.z + v.w * v.w;
    u32 lo = (u32)f2bf(v.x) | ((u32)f2bf(v.y) << 16);
    u32 hi = (u32)f2bf(v.z) | ((u32)f2bf(v.w) << 16);
    ((uint2*)(y + (size_t)row * C))[lane] = make_uint2(lo, hi);
  } else {
    float2 v = *(const float2*)src;
    s = v.x * v.x + v.y * v.y;
    ((u32*)(y + (size_t)row * C))[lane] = (u32)f2bf(v.x) | ((u32)f2bf(v.y) << 16);
  }
#pragma unroll
  for (int m = 1; m < 64; m <<= 1) s += __shfl_xor(s, m);
  if (lane == 0) nrm[row] = s;
}

template<int C>
DEV void pack_q_dev(const float* __restrict__ q, u16* __restrict__ qfb, int bid, int tid) {
  int g = bid * 256 + tid;   // [0, NQ * C/8); NQ%256==0 so cc is block-uniform
  int n = g % NQ;
  int cc = g / NQ;
  int b = n / PP, p = n % PP;
  int c0 = cc * 8;
  const float* src = q + ((size_t)b * C + c0) * PP + p;   // lanes: consecutive p -> coalesced
  s8v o;
#pragma unroll
  for (int i = 0; i < 8; ++i) o[i] = (short)f2bf(src[(size_t)i * PP]);
  ((s8v*)qfb)[((size_t)n * C + c0) >> 3] = o;
}

__global__ __launch_bounds__(256) void k_prep(
    const float* __restrict__ q2, const float* __restrict__ q3,
    const float* __restrict__ mem2, const float* __restrict__ mem3,
    const float* __restrict__ icov2, const float* __restrict__ icov3,
    u16* __restrict__ qf2b, u16* __restrict__ qf3b,
    u16* __restrict__ m2b, u16* __restrict__ m3b,
    u16* __restrict__ ic2b, u16* __restrict__ ic3b,
    float* __restrict__ mn2, float* __restrict__ mn3) {
  int bid = blockIdx.x, tid = threadIdx.x;
  if (bid < 2048)       pack_mem_dev<128>(mem2, m2b, mn2, bid, tid);
  else if (bid < 4096)  pack_mem_dev<256>(mem3, m3b, mn3, bid - 2048, tid);
  else if (bid < 4104)  pack_bf16_dev(icov2, ic2b, bid - 4096, tid);
  else if (bid < 4136)  pack_bf16_dev(icov3, ic3b, bid - 4104, tid);
  else if (bid < 4920)  pack_q_dev<128>(q2, qf2b, bid - 4136, tid);
  else                  pack_q_dev<256>(q3, qf3b, bid - 4920, tid);
}

// ================= fused distances + per-row 5 smallest d2' =================
// SWAPPED orientation: D = mfma(mem_frag, q_frag) -> rows = mem, cols = q rows.
// Each lane holds candidates for exactly 2 q-rows (col = lane&15, cb in {0,1}),
// so per-q-row top-5 lives in REGISTERS (guarded ins5) -- no d2 LDS round-trip.
// Block = 4 waves x 32 q-rows = 128 q-rows; loops over MS = MM/NSPLIT mem rows, 64/tile.
// d2' = mn - 2<q,m> (qn row-constant, added in k_combine). kp layout: [n][NSPLIT][5].
template<int C, int NSPLIT, int WPEU>
__global__ __launch_bounds__(256, WPEU)
void k_score(const u16* __restrict__ qf, const u16* __restrict__ mem,
             const float* __restrict__ mn, float* __restrict__ kp) {
  constexpr int MT = 64, MS = MM / NSPLIT, NT = MS / MT;
  constexpr int CPR = C / 8;              // 16B chunks per mem row
  constexpr int SIT = (MT * CPR) / 256;   // gl2lds iters per tile
  __shared__ alignas(16) u16 Bs[MT * C];
  __shared__ alignas(16) float mnS[MT];

  const int tid = threadIdx.x, wave = tid >> 6, lane = tid & 63;
  const int l15 = lane & 15, kb = lane >> 4, g4 = (lane >> 4) << 2;
  const int rt = blockIdx.x / NSPLIT, split = blockIdx.x % NSPLIT;
  const int row0 = rt * 128, mb0 = split * MS;

  // q fragments (B operand; loop-invariant) -> registers. q row = row0+wave*32+cb*16+l15
  bf8v qv[2][C / 32];
#pragma unroll
  for (int cb = 0; cb < 2; ++cb)
#pragma unroll
    for (int kk = 0; kk < C / 32; ++kk)
      qv[cb][kk] = *(const bf8v*)(qf + (size_t)(row0 + wave * 32 + cb * 16 + l15) * C + ((kk * 4 + kb) << 3));

  // staging: LDS linear dest, source pre-swizzled so LDS[(r, cp)] holds global chunk cp^(r&7)
  const int srow = tid / CPR, scp = tid % CPR;
  const int sswz = (scp ^ (srow & 7)) << 3;
  u16* ldst = Bs + tid * 8;

  {  // prologue: stage tile 0 (B rows + mn strip)
    const u16* src = mem + (size_t)(mb0 + srow) * C + sswz;
#pragma unroll
    for (int it = 0; it < SIT; ++it) gl2lds16(src + (size_t)it * (256 / CPR) * C, ldst + it * 2048);
    if (tid < 16) gl2lds16((const u16*)(mn + mb0) + tid * 8, (u16*)mnS + tid * 8);
  }
  __syncthreads();   // vmcnt drained -> Bs/mnS ready

  float t5[2][5];
#pragma unroll
  for (int cb = 0; cb < 2; ++cb)
#pragma unroll
    for (int i = 0; i < 5; ++i) t5[cb][i] = 1e30f;

  for (int mt = 0; mt < NT; ++mt) {
    f4v acc[4][2];   // [mb: mem 16-block][cb: q 16-block]
#pragma unroll
    for (int mb = 0; mb < 4; ++mb)
#pragma unroll
      for (int cb = 0; cb < 2; ++cb) acc[mb][cb] = (f4v){0.f, 0.f, 0.f, 0.f};
#pragma unroll
    for (int kk = 0; kk < C / 32; ++kk) {
      bf8v mf[4];
#pragma unroll
      for (int mb = 0; mb < 4; ++mb) {
        int mrow = mb * 16 + l15;
        mf[mb] = *(const bf8v*)(Bs + mrow * C + (((kk * 4 + kb) ^ (mrow & 7)) << 3));
      }
#pragma unroll
      for (int mb = 0; mb < 4; ++mb)
#pragma unroll
        for (int cb = 0; cb < 2; ++cb)
          acc[mb][cb] = __builtin_amdgcn_mfma_f32_16x16x32_bf16(mf[mb], qv[cb][kk], acc[mb][cb], 0, 0, 0);
    }
    // mem-norms for this tile (broadcast reads), BEFORE barrier
    f4v mnv[4];
#pragma unroll
    for (int mb = 0; mb < 4; ++mb) mnv[mb] = *(const f4v*)(mnS + mb * 16 + g4);
    __syncthreads();   // all Bs/mnS reads done -> safe to restage
    if (mt + 1 < NT) {
      const u16* src = mem + (size_t)(mb0 + (mt + 1) * MT + srow) * C + sswz;
#pragma unroll
      for (int it = 0; it < SIT; ++it) gl2lds16(src + (size_t)it * (256 / CPR) * C, ldst + it * 2048);
      if (tid < 16) gl2lds16((const u16*)(mn + mb0 + (mt + 1) * MT) + tid * 8, (u16*)mnS + tid * 8);
    }
    // in-register guarded top-5 update (pure VALU -> overlaps staging latency)
#pragma unroll
    for (int mb = 0; mb < 4; ++mb)
#pragma unroll
      for (int cb = 0; cb < 2; ++cb) {
        float c0 = fmaf(-2.f, acc[mb][cb][0], mnv[mb][0]);
        float c1 = fmaf(-2.f, acc[mb][cb][1], mnv[mb][1]);
        float c2 = fmaf(-2.f, acc[mb][cb][2], mnv[mb][2]);
        float c3 = fmaf(-2.f, acc[mb][cb][3], mnv[mb][3]);
        float m01 = fminf(fminf(c0, c1), fminf(c2, c3));
        if (m01 < t5[cb][4]) {
          ins5(c0, t5[cb][0], t5[cb][1], t5[cb][2], t5[cb][3], t5[cb][4]);
          ins5(c1, t5[cb][0], t5[cb][1], t5[cb][2], t5[cb][3], t5[cb][4]);
          ins5(c2, t5[cb][0], t5[cb][1], t5[cb][2], t5[cb][3], t5[cb][4]);
          ins5(c3, t5[cb][0], t5[cb][1], t5[cb][2], t5[cb][3], t5[cb][4]);
        }
      }
    __syncthreads();   // staging drained -> next tile ready
  }

  // merge across the 4 lane-groups holding the same q-col (lanes j, j+16, j+32, j+48)
#pragma unroll
  for (int cb = 0; cb < 2; ++cb) {
    float r0 = __shfl_xor(t5[cb][0], 16), r1 = __shfl_xor(t5[cb][1], 16),
          r2 = __shfl_xor(t5[cb][2], 16), r3 = __shfl_xor(t5[cb][3], 16),
          r4 = __shfl_xor(t5[cb][4], 16);
    ins5(r0, t5[cb][0], t5[cb][1], t5[cb][2], t5[cb][3], t5[cb][4]);
    ins5(r1, t5[cb][0], t5[cb][1], t5[cb][2], t5[cb][3], t5[cb][4]);
    ins5(r2, t5[cb][0], t5[cb][1], t5[cb][2], t5[cb][3], t5[cb][4]);
    ins5(r3, t5[cb][0], t5[cb][1], t5[cb][2], t5[cb][3], t5[cb][4]);
    ins5(r4, t5[cb][0], t5[cb][1], t5[cb][2], t5[cb][3], t5[cb][4]);
    r0 = __shfl_xor(t5[cb][0], 32); r1 = __shfl_xor(t5[cb][1], 32);
    r2 = __shfl_xor(t5[cb][2], 32); r3 = __shfl_xor(t5[cb][3], 32);
    r4 = __shfl_xor(t5[cb][4], 32);
    ins5(r0, t5[cb][0], t5[cb][1], t5[cb][2], t5[cb][3], t5[cb][4]);
    ins5(r1, t5[cb][0], t5[cb][1], t5[cb][2], t5[cb][3], t5[cb][4]);
    ins5(r2, t5[cb][0], t5[cb][1], t5[cb][2], t5[cb][3], t5[cb][4]);
    ins5(r3, t5[cb][0], t5[cb][1], t5[cb][2], t5[cb][3], t5[cb][4]);
    ins5(r4, t5[cb][0], t5[cb][1], t5[cb][2], t5[cb][3], t5[cb][4]);
  }
  if (lane < 16) {
#pragma unroll
    for (int cb = 0; cb < 2; ++cb) {
      int grow = row0 + wave * 32 + cb * 16 + l15;
      float* o = kp + ((size_t)grow * NSPLIT + split) * 5;
      o[0] = t5[cb][0]; o[1] = t5[cb][1]; o[2] = t5[cb][2]; o[3] = t5[cb][3]; o[4] = t5[cb][4];
    }
  }
}

// ================= fused mid: q row-norms + Mahalanobis =================
template<int C>
DEV void rownorm_dev(const u16* __restrict__ x, float* __restrict__ out, int bid, int tid) {
  int row = bid * 4 + (tid >> 6);
  int lane = tid & 63;
  constexpr int E = C / 64;
  const u16* p = x + (size_t)row * C + lane * E;
  float s = 0.f;
#pragma unroll
  for (int i = 0; i < E; ++i) { float v = bf2f(p[i]); s += v * v; }
#pragma unroll
  for (int m = 1; m < 64; m <<= 1) s += __shfl_xor(s, m);
  if (lane == 0) out[row] = s;
}

template<int C>
DEV void maha_dev(const u16* __restrict__ qfb, const float* __restrict__ mu,
                  const u16* __restrict__ icovb, float* __restrict__ mh,
                  u16* As, float* muS, int bid, int tid) {
  constexpr int QT = 64, KCH = C / 8;
  int wave = tid >> 6, lane = tid & 63;
  int row0 = bid * QT;

  for (int i = tid; i < C; i += 256) muS[i] = mu[i];
  __syncthreads();
  for (int u = tid; u < QT * KCH; u += 256) {
    int r = u / KCH, cc = u % KCH;
    bf8v v = *(const bf8v*)(qfb + (size_t)(row0 + r) * C + cc * 8);
    s8v d;
#pragma unroll
    for (int i = 0; i < 8; ++i) d[i] = (short)f2bf((float)v[i] - muS[cc * 8 + i]);
    *(s8v*)(As + r * C + ((cc ^ (r & 7)) << 3)) = d;
  }
  __syncthreads();

  int arow = wave * 16 + (lane & 15);
  int kb = lane >> 4;
  float mm[4] = {0.f, 0.f, 0.f, 0.f};
#pragma unroll
  for (int cb = 0; cb < C / 16; ++cb) {
    f4v acc = (f4v){0.f, 0.f, 0.f, 0.f};
    int bcol = cb * 16 + (lane & 15);
#pragma unroll
    for (int kk = 0; kk < C / 32; ++kk) {
      int kc = kk * 4 + kb;
      bf8v a = *(const bf8v*)(As + arow * C + ((kc ^ (arow & 7)) << 3));
      bf8v b = *(const bf8v*)(icovb + (size_t)bcol * C + kc * 8);  // global, L2-hot
      acc = __builtin_amdgcn_mfma_f32_16x16x32_bf16(a, b, acc, 0, 0, 0);
    }
#pragma unroll
    for (int r = 0; r < 4; ++r) {
      int row = wave * 16 + (lane >> 4) * 4 + r;
      int col = cb * 16 + (lane & 15);
      float dv = bf2f(As[row * C + (((col >> 3) ^ (row & 7)) << 3) + (col & 7)]);
      mm[r] += acc[r] * dv;
    }
  }
#pragma unroll
  for (int r = 0; r < 4; ++r) {
    float v = mm[r];
    v += __shfl_xor(v, 1); v += __shfl_xor(v, 2);
    v += __shfl_xor(v, 4); v += __shfl_xor(v, 8);
    if ((lane & 15) == 0)
      mh[row0 + wave * 16 + (lane >> 4) * 4 + r] = sqrtf(fmaxf(v, EPSF));
  }
}

__global__ __launch_bounds__(256) void k_mid(
    const u16* __restrict__ qf2b, const u16* __restrict__ qf3b,
    const float* __restrict__ mean2, const float* __restrict__ mean3,
    const u16* __restrict__ ic2b, const u16* __restrict__ ic3b,
    float* __restrict__ qn2, float* __restrict__ qn3,
    float* __restrict__ mh2, float* __restrict__ mh3) {
  __shared__ alignas(16) u16 As[64 * 256];
  __shared__ float muS[256];
  int bid = blockIdx.x, tid = threadIdx.x;
  if (bid < 3136)       rownorm_dev<128>(qf2b, qn2, bid, tid);
  else if (bid < 6272)  rownorm_dev<256>(qf3b, qn3, bid - 3136, tid);
  else if (bid < 6468)  maha_dev<128>(qf2b, mean2, ic2b, mh2, As, muS, bid - 6272, tid);
  else                  maha_dev<256>(qf3b, mean3, ic3b, mh3, As, muS, bid - 6468, tid);
}

// ================= combine: merge knn splits (+qn), build maps =================
// kp layout [n][S][5] -> per-thread reads are contiguous
template<int S>
DEV float knn_merge(const float* kp, int n, float qv) {
  float t0 = 1e30f, t1 = 1e30f, t2 = 1e30f, t3 = 1e30f, t4 = 1e30f;
  const float* p = kp + (size_t)n * S * 5;
#pragma unroll
  for (int i = 0; i < S * 5; ++i) ins5(p[i], t0, t1, t2, t3, t4);
  return 0.2f * (sqrtf(fmaxf(t0 + qv, EPSF)) + sqrtf(fmaxf(t1 + qv, EPSF)) +
                 sqrtf(fmaxf(t2 + qv, EPSF)) + sqrtf(fmaxf(t3 + qv, EPSF)) +
                 sqrtf(fmaxf(t4 + qv, EPSF)));
}

__global__ __launch_bounds__(256) void k_combine(
    const float* __restrict__ kp2, const float* __restrict__ kp3,
    const float* __restrict__ qn2, const float* __restrict__ qn3,
    const float* __restrict__ mh2, const float* __restrict__ mh3,
    float* __restrict__ out) {
  int n = blockIdx.x * 256 + threadIdx.x;   // exact: 49*256 == NQ
  float m2v = 0.5f * (knn_merge<16>(kp2, n, qn2[n]) + mh2[n]);
  float m3v = 0.5f * (knn_merge<8>(kp3, n, qn3[n]) + mh3[n]);
  out[16 + n] = 0.5f * (m2v + m3v);
  out[16 + NQ + n] = m2v;
  out[16 + 2 * NQ + n] = m3v;
}

// ================= per-image top-10 mean over 784-pixel map =================
__global__ __launch_bounds__(256) void k_top10(const float* __restrict__ comb, float* __restrict__ pred) {
  __shared__ float vals[1024];
  __shared__ float rv[256];
  __shared__ int ri[256];
  __shared__ float ssum;
  int b = blockIdx.x, tid = threadIdx.x;
  for (int i = tid; i < 1024; i += 256) vals[i] = (i < PP) ? comb[b * PP + i] : -1e30f;
  if (tid == 0) ssum = 0.f;
  __syncthreads();
  for (int it = 0; it < 10; ++it) {
    float bv = -1e30f; int bi = 0;
    for (int i = tid; i < 1024; i += 256) { float v = vals[i]; if (v > bv) { bv = v; bi = i; } }
    rv[tid] = bv; ri[tid] = bi;
    __syncthreads();
    for (int s = 128; s; s >>= 1) {
      if (tid < s && rv[tid + s] > rv[tid]) { rv[tid] = rv[tid + s]; ri[tid] = ri[tid + s]; }
      __syncthreads();
    }
    if (tid == 0) { ssum += rv[0]; vals[ri[0]] = -1e30f; }
    __syncthreads();
  }
  if (tid == 0) pred[b] = ssum * 0.1f;
}

extern "C" void kernel_launch(void* const* d_in, const int* in_sizes, int n_in,
                              void* d_out, int out_size, void* d_ws, size_t ws_size,
                              hipStream_t stream) {
  const float* q2    = (const float*)d_in[0];
  const float* q3    = (const float*)d_in[1];
  const float* mem2  = (const float*)d_in[2];
  const float* mem3  = (const float*)d_in[3];
  const float* mean2 = (const float*)d_in[4];
  const float* mean3 = (const float*)d_in[5];
  const float* icov2 = (const float*)d_in[6];
  const float* icov3 = (const float*)d_in[7];
  float* out = (float*)d_out;

  char* w = (char*)d_ws;
  auto alloc = [&](size_t bytes) { void* p = (void*)w; w += (bytes + 255) & ~(size_t)255; return p; };
  u16* qf2b = (u16*)alloc((size_t)NQ * 128 * 2);
  u16* qf3b = (u16*)alloc((size_t)NQ * 256 * 2);
  u16* m2b  = (u16*)alloc((size_t)MM * 128 * 2);
  u16* m3b  = (u16*)alloc((size_t)MM * 256 * 2);
  u16* ic2b = (u16*)alloc((size_t)128 * 128 * 2);
  u16* ic3b = (u16*)alloc((size_t)256 * 256 * 2);
  float* qn2 = (float*)alloc((size_t)NQ * 4);
  float* qn3 = (float*)alloc((size_t)NQ * 4);
  float* mn2 = (float*)alloc((size_t)MM * 4);
  float* mn3 = (float*)alloc((size_t)MM * 4);
  float* kp2 = (float*)alloc((size_t)NQ * 16 * 5 * 4);
  float* kp3 = (float*)alloc((size_t)NQ * 8 * 5 * 4);
  float* mh2 = (float*)alloc((size_t)NQ * 4);
  float* mh3 = (float*)alloc((size_t)NQ * 4);

  // fused prep: pack_mem2(2048) | pack_mem3(2048) | icov2(8) | icov3(32) | pack_q2(784) | pack_q3(1568)
  k_prep<<<6488, 256, 0, stream>>>(q2, q3, mem2, mem3, icov2, icov3,
                                   qf2b, qf3b, m2b, m3b, ic2b, ic3b, mn2, mn3);

  // C=256: 784 blocks (3.06/CU, LDS 33KB -> 4/CU cap); C=128: 1568 blocks
  k_score<256, 8, 4><<<(NQ / 128) * 8, 256, 0, stream>>>(qf3b, m3b, mn3, kp3);
  k_score<128, 16, 4><<<(NQ / 128) * 16, 256, 0, stream>>>(qf2b, m2b, mn2, kp2);

  // fused mid: rownorm_q2(3136) | rownorm_q3(3136) | maha128(196) | maha256(196)
  k_mid<<<6664, 256, 0, stream>>>(qf2b, qf3b, mean2, mean3, ic2b, ic3b, qn2, qn3, mh2, mh3);

  k_combine<<<NQ / 256, 256, 0, stream>>>(kp2, kp3, qn2, qn3, mh2, mh3, out);
  k_top10<<<16, 256, 0, stream>>>(out + 16, out);

  (void)in_sizes; (void)n_in; (void)out_size; (void)ws_size;
}

// Round 6
// 235.766 us; speedup vs baseline: 1.2132x; 1.0217x over previous
//
#include <hip/hip_runtime.h>

typedef unsigned short u16;
typedef unsigned int u32;
typedef __attribute__((ext_vector_type(8))) __bf16 bf8v;   // MFMA A/B operand (8 bf16)
typedef __attribute__((ext_vector_type(8))) short s8v;     // same bits, for packing
typedef __attribute__((ext_vector_type(4))) float f4v;     // MFMA C/D (16x16)

#define DEV static __device__ __forceinline__

constexpr int NQ = 12544;   // B*H*W = 16*28*28
constexpr int MM = 8192;    // memory bank rows
constexpr int PP = 784;     // H*W
constexpr float EPSF = 1e-12f;

DEV u16 f2bf(float f) {  // RNE f32 -> bf16 (inputs are finite normals)
  u32 u = __float_as_uint(f);
  return (u16)((u + 0x7FFFu + ((u >> 16) & 1u)) >> 16);
}
DEV float bf2f(u16 h) { return __uint_as_float((u32)h << 16); }

// async 16B global -> LDS (lane-linear LDS dest, per-lane global src)
DEV void gl2lds16(const u16* g, u16* l) {
  __builtin_amdgcn_global_load_lds(
      (const __attribute__((address_space(1))) unsigned int*)(g),
      (__attribute__((address_space(3))) unsigned int*)(l), 16, 0, 0);
}

// branchless sorted insert: keep 5 smallest in a0<=..<=a4
DEV void ins5(float v, float& a0, float& a1, float& a2, float& a3, float& a4) {
  float hi;
  hi = fmaxf(v, a0); a0 = fminf(v, a0); v = hi;
  hi = fmaxf(v, a1); a1 = fminf(v, a1); v = hi;
  hi = fmaxf(v, a2); a2 = fminf(v, a2); v = hi;
  hi = fmaxf(v, a3); a3 = fminf(v, a3); v = hi;
  a4 = fminf(v, a4);
}

// ================= fused prep: all f32->bf16 packs =================
DEV void pack_bf16_dev(const float* __restrict__ x, u16* __restrict__ y, int bid, int tid) {
  int g = bid * 256 + tid;
  const float4* px = (const float4*)x + (size_t)g * 2;
  float4 a = px[0], b = px[1];
  s8v o;
  o[0] = (short)f2bf(a.x); o[1] = (short)f2bf(a.y); o[2] = (short)f2bf(a.z); o[3] = (short)f2bf(a.w);
  o[4] = (short)f2bf(b.x); o[5] = (short)f2bf(b.y); o[6] = (short)f2bf(b.z); o[7] = (short)f2bf(b.w);
  ((s8v*)y)[g] = o;
}

template<int C>
DEV void pack_mem_dev(const float* __restrict__ x, u16* __restrict__ y, float* __restrict__ nrm,
                      int bid, int tid) {
  int row = bid * 4 + (tid >> 6), lane = tid & 63;
  constexpr int E = C / 64;
  const float* src = x + (size_t)row * C + lane * E;
  float s = 0.f;
  if constexpr (E == 4) {
    float4 v = *(const float4*)src;
    s = v.x * v.x + v.y * v.y + v.z * v.z + v.w * v.w;
    u32 lo = (u32)f2bf(v.x) | ((u32)f2bf(v.y) << 16);
    u32 hi = (u32)f2bf(v.z) | ((u32)f2bf(v.w) << 16);
    ((uint2*)(y + (size_t)row * C))[lane] = make_uint2(lo, hi);
  } else {
    float2 v = *(const float2*)src;
    s = v.x * v.x + v.y * v.y;
    ((u32*)(y + (size_t)row * C))[lane] = (u32)f2bf(v.x) | ((u32)f2bf(v.y) << 16);
  }
#pragma unroll
  for (int m = 1; m < 64; m <<= 1) s += __shfl_xor(s, m);
  if (lane == 0) nrm[row] = s;
}

template<int C>
DEV void pack_q_dev(const float* __restrict__ q, u16* __restrict__ qfb, int bid, int tid) {
  int g = bid * 256 + tid;   // [0, NQ * C/8); NQ%256==0 so cc is block-uniform
  int n = g % NQ;
  int cc = g / NQ;
  int b = n / PP, p = n % PP;
  int c0 = cc * 8;
  const float* src = q + ((size_t)b * C + c0) * PP + p;   // lanes: consecutive p -> coalesced
  s8v o;
#pragma unroll
  for (int i = 0; i < 8; ++i) o[i] = (short)f2bf(src[(size_t)i * PP]);
  ((s8v*)qfb)[((size_t)n * C + c0) >> 3] = o;
}

__global__ __launch_bounds__(256) void k_prep(
    const float* __restrict__ q2, const float* __restrict__ q3,
    const float* __restrict__ mem2, const float* __restrict__ mem3,
    const float* __restrict__ icov2, const float* __restrict__ icov3,
    u16* __restrict__ qf2b, u16* __restrict__ qf3b,
    u16* __restrict__ m2b, u16* __restrict__ m3b,
    u16* __restrict__ ic2b, u16* __restrict__ ic3b,
    float* __restrict__ mn2, float* __restrict__ mn3) {
  int bid = blockIdx.x, tid = threadIdx.x;
  if (bid < 2048)       pack_mem_dev<128>(mem2, m2b, mn2, bid, tid);
  else if (bid < 4096)  pack_mem_dev<256>(mem3, m3b, mn3, bid - 2048, tid);
  else if (bid < 4104)  pack_bf16_dev(icov2, ic2b, bid - 4096, tid);
  else if (bid < 4136)  pack_bf16_dev(icov3, ic3b, bid - 4104, tid);
  else if (bid < 4920)  pack_q_dev<128>(q2, qf2b, bid - 4136, tid);
  else                  pack_q_dev<256>(q3, qf3b, bid - 4920, tid);
}

// ================= fused distances + per-row 5 smallest d2' =================
// SWAPPED orientation: D = mfma(mem_frag, q_frag) -> rows = mem, cols = q rows;
// per-q-row top-5 lives in registers. DOUBLE-BUFFERED LDS staging (T3 2-phase):
// issue STAGE(buf^1, t+1) BEFORE computing on buf -> staging latency hides under
// MFMA+scan; ONE barrier per tile (its implicit vmcnt(0) drain lands after overlap).
// WPEU sized so q fragments stay register-resident (R5 lesson: VGPR=64 => reloads).
template<int C, int NSPLIT, int WPEU>
__global__ __launch_bounds__(256, WPEU)
void k_score(const u16* __restrict__ qf, const u16* __restrict__ mem,
             const float* __restrict__ mn, float* __restrict__ kp) {
  constexpr int MT = 64, MS = MM / NSPLIT, NT = MS / MT;
  constexpr int CPR = C / 8;              // 16B chunks per mem row
  constexpr int SIT = (MT * CPR) / 256;   // gl2lds iters per tile (8 @C=256, 4 @C=128)
  constexpr int RPI = 256 / CPR;          // rows staged per iter
  __shared__ alignas(16) u16 Bs[2][MT * C];
  __shared__ alignas(16) float mnS[2][MT];

  const int tid = threadIdx.x, wave = tid >> 6, lane = tid & 63;
  const int l15 = lane & 15, kb = lane >> 4, g4 = (lane >> 4) << 2;
  const int rt = blockIdx.x / NSPLIT, split = blockIdx.x % NSPLIT;
  const int row0 = rt * 128, mb0 = split * MS;

  // q fragments (B operand; loop-invariant) -> registers. q row = row0+wave*32+cb*16+l15
  bf8v qv[2][C / 32];
#pragma unroll
  for (int cb = 0; cb < 2; ++cb)
#pragma unroll
    for (int kk = 0; kk < C / 32; ++kk)
      qv[cb][kk] = *(const bf8v*)(qf + (size_t)(row0 + wave * 32 + cb * 16 + l15) * C + ((kk * 4 + kb) << 3));

  // staging: LDS linear dest, source pre-swizzled so LDS[(r, cp)] holds global chunk cp^(r&7)
  const int srow = tid / CPR, scp = tid % CPR;
  const int sswz = (scp ^ (srow & 7)) << 3;

  auto STAGE = [&](int buf, int mt) {
    const u16* src = mem + (size_t)(mb0 + mt * MT + srow) * C + sswz;
    u16* dst = Bs[buf] + tid * 8;
#pragma unroll
    for (int it = 0; it < SIT; ++it) gl2lds16(src + (size_t)it * RPI * C, dst + it * 2048);
    if (tid < 16) gl2lds16((const u16*)(mn + mb0 + mt * MT) + tid * 8, (u16*)mnS[buf] + tid * 8);
  };

  STAGE(0, 0);
  __syncthreads();   // vmcnt drained -> buf0 ready

  float t5[2][5];
#pragma unroll
  for (int cb = 0; cb < 2; ++cb)
#pragma unroll
    for (int i = 0; i < 5; ++i) t5[cb][i] = 1e30f;

  for (int mt = 0; mt < NT; ++mt) {
    const int cur = mt & 1;
    if (mt + 1 < NT) STAGE(cur ^ 1, mt + 1);   // async prefetch into other buffer

    const u16* B = Bs[cur];
    f4v acc[4][2];   // [mb: mem 16-block][cb: q 16-block]
#pragma unroll
    for (int mb = 0; mb < 4; ++mb)
#pragma unroll
      for (int cb = 0; cb < 2; ++cb) acc[mb][cb] = (f4v){0.f, 0.f, 0.f, 0.f};
#pragma unroll
    for (int kk = 0; kk < C / 32; ++kk) {
      bf8v mf[4];
#pragma unroll
      for (int mb = 0; mb < 4; ++mb) {
        int mrow = mb * 16 + l15;
        mf[mb] = *(const bf8v*)(B + mrow * C + (((kk * 4 + kb) ^ (mrow & 7)) << 3));
      }
#pragma unroll
      for (int mb = 0; mb < 4; ++mb)
#pragma unroll
        for (int cb = 0; cb < 2; ++cb)
          acc[mb][cb] = __builtin_amdgcn_mfma_f32_16x16x32_bf16(mf[mb], qv[cb][kk], acc[mb][cb], 0, 0, 0);
    }
    f4v mnv[4];
#pragma unroll
    for (int mb = 0; mb < 4; ++mb) mnv[mb] = *(const f4v*)(mnS[cur] + mb * 16 + g4);

    // in-register guarded top-5 update (pure VALU -> overlaps staging latency)
#pragma unroll
    for (int mb = 0; mb < 4; ++mb)
#pragma unroll
      for (int cb = 0; cb < 2; ++cb) {
        float c0 = fmaf(-2.f, acc[mb][cb][0], mnv[mb][0]);
        float c1 = fmaf(-2.f, acc[mb][cb][1], mnv[mb][1]);
        float c2 = fmaf(-2.f, acc[mb][cb][2], mnv[mb][2]);
        float c3 = fmaf(-2.f, acc[mb][cb][3], mnv[mb][3]);
        float m01 = fminf(fminf(c0, c1), fminf(c2, c3));
        if (m01 < t5[cb][4]) {
          ins5(c0, t5[cb][0], t5[cb][1], t5[cb][2], t5[cb][3], t5[cb][4]);
          ins5(c1, t5[cb][0], t5[cb][1], t5[cb][2], t5[cb][3], t5[cb][4]);
          ins5(c2, t5[cb][0], t5[cb][1], t5[cb][2], t5[cb][3], t5[cb][4]);
          ins5(c3, t5[cb][0], t5[cb][1], t5[cb][2], t5[cb][3], t5[cb][4]);
        }
      }
    __syncthreads();   // staging of buf^1 drained; Bs[cur] reads done -> next tile
  }

  // merge across the 4 lane-groups holding the same q-col (lanes j, j+16, j+32, j+48)
#pragma unroll
  for (int cb = 0; cb < 2; ++cb) {
    float r0 = __shfl_xor(t5[cb][0], 16), r1 = __shfl_xor(t5[cb][1], 16),
          r2 = __shfl_xor(t5[cb][2], 16), r3 = __shfl_xor(t5[cb][3], 16),
          r4 = __shfl_xor(t5[cb][4], 16);
    ins5(r0, t5[cb][0], t5[cb][1], t5[cb][2], t5[cb][3], t5[cb][4]);
    ins5(r1, t5[cb][0], t5[cb][1], t5[cb][2], t5[cb][3], t5[cb][4]);
    ins5(r2, t5[cb][0], t5[cb][1], t5[cb][2], t5[cb][3], t5[cb][4]);
    ins5(r3, t5[cb][0], t5[cb][1], t5[cb][2], t5[cb][3], t5[cb][4]);
    ins5(r4, t5[cb][0], t5[cb][1], t5[cb][2], t5[cb][3], t5[cb][4]);
    r0 = __shfl_xor(t5[cb][0], 32); r1 = __shfl_xor(t5[cb][1], 32);
    r2 = __shfl_xor(t5[cb][2], 32); r3 = __shfl_xor(t5[cb][3], 32);
    r4 = __shfl_xor(t5[cb][4], 32);
    ins5(r0, t5[cb][0], t5[cb][1], t5[cb][2], t5[cb][3], t5[cb][4]);
    ins5(r1, t5[cb][0], t5[cb][1], t5[cb][2], t5[cb][3], t5[cb][4]);
    ins5(r2, t5[cb][0], t5[cb][1], t5[cb][2], t5[cb][3], t5[cb][4]);
    ins5(r3, t5[cb][0], t5[cb][1], t5[cb][2], t5[cb][3], t5[cb][4]);
    ins5(r4, t5[cb][0], t5[cb][1], t5[cb][2], t5[cb][3], t5[cb][4]);
  }
  if (lane < 16) {
#pragma unroll
    for (int cb = 0; cb < 2; ++cb) {
      int grow = row0 + wave * 32 + cb * 16 + l15;
      float* o = kp + ((size_t)grow * NSPLIT + split) * 5;
      o[0] = t5[cb][0]; o[1] = t5[cb][1]; o[2] = t5[cb][2]; o[3] = t5[cb][3]; o[4] = t5[cb][4];
    }
  }
}

// ================= fused mid: q row-norms + Mahalanobis =================
template<int C>
DEV void rownorm_dev(const u16* __restrict__ x, float* __restrict__ out, int bid, int tid) {
  int row = bid * 4 + (tid >> 6);
  int lane = tid & 63;
  constexpr int E = C / 64;
  const u16* p = x + (size_t)row * C + lane * E;
  float s = 0.f;
#pragma unroll
  for (int i = 0; i < E; ++i) { float v = bf2f(p[i]); s += v * v; }
#pragma unroll
  for (int m = 1; m < 64; m <<= 1) s += __shfl_xor(s, m);
  if (lane == 0) out[row] = s;
}

template<int C>
DEV void maha_dev(const u16* __restrict__ qfb, const float* __restrict__ mu,
                  const u16* __restrict__ icovb, float* __restrict__ mh,
                  u16* As, float* muS, int bid, int tid) {
  constexpr int QT = 64, KCH = C / 8;
  int wave = tid >> 6, lane = tid & 63;
  int row0 = bid * QT;

  for (int i = tid; i < C; i += 256) muS[i] = mu[i];
  __syncthreads();
  for (int u = tid; u < QT * KCH; u += 256) {
    int r = u / KCH, cc = u % KCH;
    bf8v v = *(const bf8v*)(qfb + (size_t)(row0 + r) * C + cc * 8);
    s8v d;
#pragma unroll
    for (int i = 0; i < 8; ++i) d[i] = (short)f2bf((float)v[i] - muS[cc * 8 + i]);
    *(s8v*)(As + r * C + ((cc ^ (r & 7)) << 3)) = d;
  }
  __syncthreads();

  int arow = wave * 16 + (lane & 15);
  int kb = lane >> 4;
  float mm[4] = {0.f, 0.f, 0.f, 0.f};
#pragma unroll
  for (int cb = 0; cb < C / 16; ++cb) {
    f4v acc = (f4v){0.f, 0.f, 0.f, 0.f};
    int bcol = cb * 16 + (lane & 15);
#pragma unroll
    for (int kk = 0; kk < C / 32; ++kk) {
      int kc = kk * 4 + kb;
      bf8v a = *(const bf8v*)(As + arow * C + ((kc ^ (arow & 7)) << 3));
      bf8v b = *(const bf8v*)(icovb + (size_t)bcol * C + kc * 8);  // global, L2-hot
      acc = __builtin_amdgcn_mfma_f32_16x16x32_bf16(a, b, acc, 0, 0, 0);
    }
#pragma unroll
    for (int r = 0; r < 4; ++r) {
      int row = wave * 16 + (lane >> 4) * 4 + r;
      int col = cb * 16 + (lane & 15);
      float dv = bf2f(As[row * C + (((col >> 3) ^ (row & 7)) << 3) + (col & 7)]);
      mm[r] += acc[r] * dv;
    }
  }
#pragma unroll
  for (int r = 0; r < 4; ++r) {
    float v = mm[r];
    v += __shfl_xor(v, 1); v += __shfl_xor(v, 2);
    v += __shfl_xor(v, 4); v += __shfl_xor(v, 8);
    if ((lane & 15) == 0)
      mh[row0 + wave * 16 + (lane >> 4) * 4 + r] = sqrtf(fmaxf(v, EPSF));
  }
}

__global__ __launch_bounds__(256) void k_mid(
    const u16* __restrict__ qf2b, const u16* __restrict__ qf3b,
    const float* __restrict__ mean2, const float* __restrict__ mean3,
    const u16* __restrict__ ic2b, const u16* __restrict__ ic3b,
    float* __restrict__ qn2, float* __restrict__ qn3,
    float* __restrict__ mh2, float* __restrict__ mh3) {
  __shared__ alignas(16) u16 As[64 * 256];
  __shared__ float muS[256];
  int bid = blockIdx.x, tid = threadIdx.x;
  if (bid < 3136)       rownorm_dev<128>(qf2b, qn2, bid, tid);
  else if (bid < 6272)  rownorm_dev<256>(qf3b, qn3, bid - 3136, tid);
  else if (bid < 6468)  maha_dev<128>(qf2b, mean2, ic2b, mh2, As, muS, bid - 6272, tid);
  else                  maha_dev<256>(qf3b, mean3, ic3b, mh3, As, muS, bid - 6468, tid);
}

// ================= combine: merge knn splits (+qn), build maps =================
// kp layout [n][S][5] -> per-thread reads are contiguous
template<int S>
DEV float knn_merge(const float* kp, int n, float qv) {
  float t0 = 1e30f, t1 = 1e30f, t2 = 1e30f, t3 = 1e30f, t4 = 1e30f;
  const float* p = kp + (size_t)n * S * 5;
#pragma unroll
  for (int i = 0; i < S * 5; ++i) ins5(p[i], t0, t1, t2, t3, t4);
  return 0.2f * (sqrtf(fmaxf(t0 + qv, EPSF)) + sqrtf(fmaxf(t1 + qv, EPSF)) +
                 sqrtf(fmaxf(t2 + qv, EPSF)) + sqrtf(fmaxf(t3 + qv, EPSF)) +
                 sqrtf(fmaxf(t4 + qv, EPSF)));
}

__global__ __launch_bounds__(256) void k_combine(
    const float* __restrict__ kp2, const float* __restrict__ kp3,
    const float* __restrict__ qn2, const float* __restrict__ qn3,
    const float* __restrict__ mh2, const float* __restrict__ mh3,
    float* __restrict__ out) {
  int n = blockIdx.x * 256 + threadIdx.x;   // exact: 49*256 == NQ
  float m2v = 0.5f * (knn_merge<16>(kp2, n, qn2[n]) + mh2[n]);
  float m3v = 0.5f * (knn_merge<8>(kp3, n, qn3[n]) + mh3[n]);
  out[16 + n] = 0.5f * (m2v + m3v);
  out[16 + NQ + n] = m2v;
  out[16 + 2 * NQ + n] = m3v;
}

// ================= per-image top-10 mean over 784-pixel map =================
__global__ __launch_bounds__(256) void k_top10(const float* __restrict__ comb, float* __restrict__ pred) {
  __shared__ float vals[1024];
  __shared__ float rv[256];
  __shared__ int ri[256];
  __shared__ float ssum;
  int b = blockIdx.x, tid = threadIdx.x;
  for (int i = tid; i < 1024; i += 256) vals[i] = (i < PP) ? comb[b * PP + i] : -1e30f;
  if (tid == 0) ssum = 0.f;
  __syncthreads();
  for (int it = 0; it < 10; ++it) {
    float bv = -1e30f; int bi = 0;
    for (int i = tid; i < 1024; i += 256) { float v = vals[i]; if (v > bv) { bv = v; bi = i; } }
    rv[tid] = bv; ri[tid] = bi;
    __syncthreads();
    for (int s = 128; s; s >>= 1) {
      if (tid < s && rv[tid + s] > rv[tid]) { rv[tid] = rv[tid + s]; ri[tid] = ri[tid + s]; }
      __syncthreads();
    }
    if (tid == 0) { ssum += rv[0]; vals[ri[0]] = -1e30f; }
    __syncthreads();
  }
  if (tid == 0) pred[b] = ssum * 0.1f;
}

extern "C" void kernel_launch(void* const* d_in, const int* in_sizes, int n_in,
                              void* d_out, int out_size, void* d_ws, size_t ws_size,
                              hipStream_t stream) {
  const float* q2    = (const float*)d_in[0];
  const float* q3    = (const float*)d_in[1];
  const float* mem2  = (const float*)d_in[2];
  const float* mem3  = (const float*)d_in[3];
  const float* mean2 = (const float*)d_in[4];
  const float* mean3 = (const float*)d_in[5];
  const float* icov2 = (const float*)d_in[6];
  const float* icov3 = (const float*)d_in[7];
  float* out = (float*)d_out;

  char* w = (char*)d_ws;
  auto alloc = [&](size_t bytes) { void* p = (void*)w; w += (bytes + 255) & ~(size_t)255; return p; };
  u16* qf2b = (u16*)alloc((size_t)NQ * 128 * 2);
  u16* qf3b = (u16*)alloc((size_t)NQ * 256 * 2);
  u16* m2b  = (u16*)alloc((size_t)MM * 128 * 2);
  u16* m3b  = (u16*)alloc((size_t)MM * 256 * 2);
  u16* ic2b = (u16*)alloc((size_t)128 * 128 * 2);
  u16* ic3b = (u16*)alloc((size_t)256 * 256 * 2);
  float* qn2 = (float*)alloc((size_t)NQ * 4);
  float* qn3 = (float*)alloc((size_t)NQ * 4);
  float* mn2 = (float*)alloc((size_t)MM * 4);
  float* mn3 = (float*)alloc((size_t)MM * 4);
  float* kp2 = (float*)alloc((size_t)NQ * 16 * 5 * 4);
  float* kp3 = (float*)alloc((size_t)NQ * 8 * 5 * 4);
  float* mh2 = (float*)alloc((size_t)NQ * 4);
  float* mh3 = (float*)alloc((size_t)NQ * 4);

  // fused prep: pack_mem2(2048) | pack_mem3(2048) | icov2(8) | icov3(32) | pack_q2(784) | pack_q3(1568)
  k_prep<<<6488, 256, 0, stream>>>(q2, q3, mem2, mem3, icov2, icov3,
                                   qf2b, qf3b, m2b, m3b, ic2b, ic3b, mn2, mn3);

  // C=256: dbuf LDS 65KB -> 2 blocks/CU (WPEU=2, VGPR<=256 keeps qv resident)
  // C=128: dbuf LDS 33KB -> WPEU=3 (VGPR<=170)
  k_score<256, 8, 2><<<(NQ / 128) * 8, 256, 0, stream>>>(qf3b, m3b, mn3, kp3);
  k_score<128, 16, 3><<<(NQ / 128) * 16, 256, 0, stream>>>(qf2b, m2b, mn2, kp2);

  // fused mid: rownorm_q2(3136) | rownorm_q3(3136) | maha128(196) | maha256(196)
  k_mid<<<6664, 256, 0, stream>>>(qf2b, qf3b, mean2, mean3, ic2b, ic3b, qn2, qn3, mh2, mh3);

  k_combine<<<NQ / 256, 256, 0, stream>>>(kp2, kp3, qn2, qn3, mh2, mh3, out);
  k_top10<<<16, 256, 0, stream>>>(out + 16, out);

  (void)in_sizes; (void)n_in; (void)out_size; (void)ws_size;
}